// Round 7
// baseline (26.941 us; speedup 1.0000x reference)
//
#include <hip/hip_runtime.h>
#include <hip/hip_bf16.h>
#include <hip/hip_fp16.h>

// ---- problem constants ----
#define NG 1024
#define IMW 256
#define IMH 192
#define NPIX (IMW*IMH)
#define FXc 220.0f
#define FYc 220.0f
#define CXc 128.0f
#define CYc 96.0f
#define NEARc 0.01f
#define FARc 10.0f
#define ALPHA_THRc 1e-5f

// SH constants
#define SH_C0 0.28209479177387814f
#define SH_C1 0.4886025119029199f
#define SH_C2_0 1.0925484305920792f
#define SH_C2_1 (-1.0925484305920792f)
#define SH_C2_2 0.31539156525252005f
#define SH_C2_3 (-1.0925484305920792f)
#define SH_C2_4 0.5462742152960396f
#define SH_C3_0 (-0.5900435899266435f)
#define SH_C3_1 2.890611442640554f
#define SH_C3_2 (-0.4570457994644658f)
#define SH_C3_3 0.3731763325901154f
#define SH_C3_4 (-0.4570457994644658f)
#define SH_C3_5 1.445305721320277f
#define SH_C3_6 (-0.5900435899266435f)

// Single fused kernel: one 16x16 pixel tile per 256-thread block (192 blocks,
// ~1/CU). Each block redundantly computes the cheap projection/cov math for
// all NG gaussians (4/thread), culls against its tile, appends survivors to
// LDS (atomicAdd slot order is nondeterministic, but the rank sort over
// unique (z|idx) keys makes the processed sequence -- and thus the FP
// result -- deterministic). SH color (the expensive part) is evaluated for
// survivors only, fused with the rank loop. Composite is barrier-free.
__global__ __launch_bounds__(256)
void gs_fused(const float* __restrict__ pos, const float* __restrict__ rot,
              const float* __restrict__ scl, const float* __restrict__ opac,
              const float* __restrict__ sh,  const float* __restrict__ Twc,
              float* __restrict__ out) {
    __shared__ float4 sv0[NG];                 // (u,v,A,B)          16 KB
    __shared__ float4 sv1[NG];                 // (C,op,xc,yc)->(C,op,rg,bz) 16 KB
    __shared__ unsigned long long key[NG];     // (zbits|idx)         8 KB
    __shared__ unsigned short ord[NG];         //                     2 KB
    __shared__ int scnt;

    int t = threadIdx.x;
    if (t == 0) scnt = 0;
    __syncthreads();

    float tx0 = (float)(blockIdx.x * 16) + 0.5f;
    float tx1 = tx0 + 15.0f;
    float ty0 = (float)(blockIdx.y * 16) + 0.5f;
    float ty1 = ty0 + 15.0f;

    float T0 = Twc[0],  T1 = Twc[1],  T2 = Twc[2],  T3 = Twc[3];
    float T4 = Twc[4],  T5 = Twc[5],  T6 = Twc[6],  T7 = Twc[7];
    float T8 = Twc[8],  T9 = Twc[9],  T10 = Twc[10], T11 = Twc[11];

    const float xfac = fmaxf(CXc/FXc, (IMW - CXc)/FXc) * 1.1f;   // (1+MARGIN)
    const float yfac = fmaxf(CYc/FYc, (IMH - CYc)/FYc) * 1.1f;

    // --- phase 1: cheap prep + cull for all NG, 4 per thread ---
    for (int p = 0; p < 4; ++p) {
        int i = p * 256 + t;
        float p0 = pos[i*3+0], p1 = pos[i*3+1], p2 = pos[i*3+2];
        float xc = T0*p0 + T1*p1 + T2*p2  + T3;
        float yc = T4*p0 + T5*p1 + T6*p2  + T7;
        float zc = T8*p0 + T9*p1 + T10*p2 + T11;
        float az = fabsf(zc);
        bool valid = (az > NEARc) && (az < FARc) &&
                     (fabsf(xc) < az * xfac) && (fabsf(yc) < az * yfac);
        float op = opac[i];
        if (!(valid && op > 0.0f)) continue;

        float zs = (az < 1e-8f) ? 1e-8f : zc;
        float iz = 1.0f / zs;
        float u = FXc * xc * iz + CXc;
        float v = FYc * yc * iz + CYc;

        float qw = rot[i*4+0], qx = rot[i*4+1], qy = rot[i*4+2], qz = rot[i*4+3];
        float qn = sqrtf(qw*qw + qx*qx + qy*qy + qz*qz) + 1e-12f;
        float inq = 1.0f / qn;
        qw *= inq; qx *= inq; qy *= inq; qz *= inq;
        float R00 = 1.0f - 2.0f*(qy*qy + qz*qz);
        float R01 = 2.0f*(qx*qy - qw*qz);
        float R02 = 2.0f*(qx*qz + qw*qy);
        float R10 = 2.0f*(qx*qy + qw*qz);
        float R11 = 1.0f - 2.0f*(qx*qx + qz*qz);
        float R12 = 2.0f*(qy*qz - qw*qx);
        float R20 = 2.0f*(qx*qz - qw*qy);
        float R21 = 2.0f*(qy*qz + qw*qx);
        float R22 = 1.0f - 2.0f*(qx*qx + qy*qy);

        float s0 = expf(scl[i*3+0]);
        float s1 = expf(scl[i*3+1]);
        float s2 = expf(scl[i*3+2]);
        float M00 = R00*s0, M01 = R01*s1, M02 = R02*s2;
        float M10 = R10*s0, M11 = R11*s1, M12 = R12*s2;
        float M20 = R20*s0, M21 = R21*s1, M22 = R22*s2;

        float S00 = M00*M00 + M01*M01 + M02*M02;
        float S01 = M00*M10 + M01*M11 + M02*M12;
        float S02 = M00*M20 + M01*M21 + M02*M22;
        float S11 = M10*M10 + M11*M11 + M12*M12;
        float S12 = M10*M20 + M11*M21 + M12*M22;
        float S22 = M20*M20 + M21*M21 + M22*M22;

        float j00 = FXc * iz,  j02 = -FXc * xc * iz * iz;
        float j11 = FYc * iz,  j12 = -FYc * yc * iz * iz;
        float c00 = j00*j00*S00 + 2.0f*j00*j02*S02 + j02*j02*S22 + 0.3f;
        float c01 = j00*j11*S01 + j00*j12*S02 + j02*j11*S12 + j02*j12*S22;
        float c11 = j11*j11*S11 + 2.0f*j11*j12*S12 + j12*j12*S22 + 0.3f;

        float Q = fmaxf(2.0f * logf(fmaxf(op, 1e-20f) * 1e5f), 0.0f);
        float rx = sqrtf(Q * c00) + 1e-3f;
        float ry = sqrtf(Q * c11) + 1e-3f;

        bool pass = (u + rx >= tx0) && (u - rx <= tx1) &&
                    (v + ry >= ty0) && (v - ry <= ty1);
        if (!pass) continue;

        float det = fmaxf(c00*c11 - c01*c01, 1e-12f);
        float idet = 1.0f / det;

        int slot = atomicAdd(&scnt, 1);
        sv0[slot] = make_float4(u, v, c11*idet, -c01*idet);
        sv1[slot] = make_float4(c00*idet, op, xc, yc);
        unsigned int zb = __float_as_uint(zc);
        zb = (zb & 0x80000000u) ? ~zb : (zb | 0x80000000u);   // monotone
        key[slot] = ((unsigned long long)zb << 32) | (unsigned int)(NG - 1 - i);
    }
    __syncthreads();
    int M = scnt;

    // --- phase 2: rank (vs all M unique keys) + SH color, survivors only ---
    for (int s = t; s < M; s += 256) {
        unsigned long long ks = key[s];
        int rank = 0;
        for (int j = 0; j < M; ++j)
            rank += (key[j] < ks) ? 1 : 0;

        unsigned int zb = (unsigned int)(ks >> 32);
        unsigned int zorig = (zb & 0x80000000u) ? (zb & 0x7fffffffu) : ~zb;
        float zc = __uint_as_float(zorig);
        int i = NG - 1 - (int)(ks & 0xFFFFFFFFu);
        float4 a1 = sv1[s];
        float xc = a1.z, yc = a1.w;

        float pn = sqrtf(xc*xc + yc*yc + zc*zc) + 1e-12f;
        float ipn = 1.0f / pn;
        float dx = xc*ipn, dy = yc*ipn, dz = zc*ipn;
        float xx = dx*dx, yy = dy*dy, zz = dz*dz;
        float xy = dx*dy, yz = dy*dz, xz = dx*dz;

        const float* sp = sh + i*48;
        float col[3];
#pragma unroll
        for (int ch = 0; ch < 3; ++ch) {
            float c = SH_C0*sp[0+ch] - SH_C1*dy*sp[3+ch] + SH_C1*dz*sp[6+ch] - SH_C1*dx*sp[9+ch];
            c += SH_C2_0*xy*sp[12+ch] + SH_C2_1*yz*sp[15+ch] + SH_C2_2*(2.0f*zz-xx-yy)*sp[18+ch]
               + SH_C2_3*xz*sp[21+ch] + SH_C2_4*(xx-yy)*sp[24+ch];
            c += SH_C3_0*dy*(3.0f*xx-yy)*sp[27+ch] + SH_C3_1*xy*dz*sp[30+ch]
               + SH_C3_2*dy*(4.0f*zz-xx-yy)*sp[33+ch] + SH_C3_3*dz*(2.0f*zz-3.0f*xx-3.0f*yy)*sp[36+ch]
               + SH_C3_4*dx*(4.0f*zz-xx-yy)*sp[39+ch] + SH_C3_5*dz*(xx-yy)*sp[42+ch]
               + SH_C3_6*dx*(xx-3.0f*yy)*sp[45+ch];
            col[ch] = fminf(fmaxf(c + 0.5f, 0.0f), 1.0f);
        }
        __half2 rg = __floats2half2_rn(col[0], col[1]);
        __half2 bz = __floats2half2_rn(col[2], zc);
        sv1[s] = make_float4(a1.x, a1.y, __uint_as_float(*(unsigned int*)&rg),
                                          __uint_as_float(*(unsigned int*)&bz));
        ord[rank] = (unsigned short)s;
    }
    __syncthreads();

    // --- phase 3: composite front-to-back (barrier-free, waves independent) ---
    float px = tx0 + (float)(t & 15);
    float py = ty0 + (float)(t >> 4);
    float T = 1.0f;
    float cr = 0.0f, cg = 0.0f, cb = 0.0f, cd = 0.0f;

    for (int j = 0; j < M; ++j) {
        int slot = ord[j];
        float4 b0 = sv0[slot];
        float4 b1 = sv1[slot];
        float dx = px - b0.x;
        float dy = py - b0.y;
        float pw = -0.5f * (b0.z * dx * dx + b1.x * dy * dy) - b0.w * dx * dy;
        pw = fminf(pw, 0.0f);
        float alpha = fminf(0.99f, b1.y * __expf(pw));
        float aeff = (alpha >= ALPHA_THRc) ? alpha : 0.0f;
        float w = aeff * T;
        float2 rg = __half22float2(*(__half2*)&b1.z);
        float2 bz = __half22float2(*(__half2*)&b1.w);
        cr += w * rg.x;
        cg += w * rg.y;
        cb += w * bz.x;
        cd += w * bz.y;
        T *= 1.0f - aeff;
        if (__all(T < 1e-4f)) break;
    }

    int x = blockIdx.x * 16 + (t & 15);
    int y = blockIdx.y * 16 + (t >> 4);
    int idx = y * IMW + x;
    out[idx*3 + 0] = cr;
    out[idx*3 + 1] = cg;
    out[idx*3 + 2] = cb;
    out[NPIX*3 + idx] = cd;
}

extern "C" void kernel_launch(void* const* d_in, const int* in_sizes, int n_in,
                              void* d_out, int out_size, void* d_ws, size_t ws_size,
                              hipStream_t stream) {
    const float* pos  = (const float*)d_in[0];
    const float* rot  = (const float*)d_in[1];
    const float* scl  = (const float*)d_in[2];
    const float* opac = (const float*)d_in[3];
    const float* sh   = (const float*)d_in[4];
    const float* Twc  = (const float*)d_in[5];
    float* out = (float*)d_out;

    gs_fused<<<dim3(IMW/16, IMH/16), dim3(256), 0, stream>>>(
        pos, rot, scl, opac, sh, Twc, out);
}

// Round 8
// 26.259 us; speedup vs baseline: 1.0260x; 1.0260x over previous
//
#include <hip/hip_runtime.h>
#include <hip/hip_bf16.h>
#include <hip/hip_fp16.h>

// ---- problem constants ----
#define NG 1024
#define IMW 256
#define IMH 192
#define NPIX (IMW*IMH)
#define FXc 220.0f
#define FYc 220.0f
#define CXc 128.0f
#define CYc 96.0f
#define NEARc 0.01f
#define FARc 10.0f
#define ALPHA_THRc 1e-5f

// SH constants
#define SH_C0 0.28209479177387814f
#define SH_C1 0.4886025119029199f
#define SH_C2_0 1.0925484305920792f
#define SH_C2_1 (-1.0925484305920792f)
#define SH_C2_2 0.31539156525252005f
#define SH_C2_3 (-1.0925484305920792f)
#define SH_C2_4 0.5462742152960396f
#define SH_C3_0 (-0.5900435899266435f)
#define SH_C3_1 2.890611442640554f
#define SH_C3_2 (-0.4570457994644658f)
#define SH_C3_3 0.3731763325901154f
#define SH_C3_4 (-0.4570457994644658f)
#define SH_C3_5 1.445305721320277f
#define SH_C3_6 (-0.5900435899266435f)

// ws layout (bytes), all rewritten every call, sorted by (z asc, idx desc):
//   c0 float4[NG] @ 0     : (u,v,rx,ry)   cull record; rx=-1e9 marks invalid
//   g1 float4[NG] @ 16384 : (A,B,C,op)    survivor record 1
//   g2 float2[NG] @ 32768 : (h2(r,g), h2(b,z)) survivor record 2

// Fused prep + global counting sort. 16 blocks x 256 threads.
__global__ __launch_bounds__(256)
void gs_prepsort(const float* __restrict__ pos, const float* __restrict__ rot,
                 const float* __restrict__ scl, const float* __restrict__ opac,
                 const float* __restrict__ sh,  const float* __restrict__ Twc,
                 float4* __restrict__ c0, float4* __restrict__ g1,
                 float2* __restrict__ g2) {
    __shared__ unsigned long long keys[NG];   // 8 KB
    __shared__ int pr[256];

    int t = threadIdx.x;
    int b = blockIdx.x;

    float T0 = Twc[0],  T1 = Twc[1],  T2 = Twc[2],  T3 = Twc[3];
    float T4 = Twc[4],  T5 = Twc[5],  T6 = Twc[6],  T7 = Twc[7];
    float T8 = Twc[8],  T9 = Twc[9],  T10 = Twc[10], T11 = Twc[11];

    const float xfac = fmaxf(CXc/FXc, (IMW - CXc)/FXc) * 1.1f;   // (1+MARGIN)
    const float yfac = fmaxf(CYc/FYc, (IMH - CYc)/FYc) * 1.1f;

    // --- phase A: keys for all NG ---
#pragma unroll
    for (int p = 0; p < 4; ++p) {
        int i = p * 256 + t;
        float p0 = pos[i*3+0], p1 = pos[i*3+1], p2 = pos[i*3+2];
        float xc = T0*p0 + T1*p1 + T2*p2  + T3;
        float yc = T4*p0 + T5*p1 + T6*p2  + T7;
        float zc = T8*p0 + T9*p1 + T10*p2 + T11;
        float az = fabsf(zc);
        bool valid = (az > NEARc) && (az < FARc) &&
                     (fabsf(xc) < az * xfac) && (fabsf(yc) < az * yfac);
        bool keep = valid && (opac[i] > 0.0f);
        unsigned int zb = __float_as_uint(zc);
        zb = (zb & 0x80000000u) ? ~zb : (zb | 0x80000000u);   // monotone
        unsigned int lo = (unsigned int)(NG - 1 - i);         // idx desc on ties
        keys[i] = keep ? (((unsigned long long)zb << 32) | lo)
                       : ((0xFFFFFFFFull << 32) | lo);        // unique tail
    }
    __syncthreads();

    // --- phase B1: rank own 64 against all NG (4-way split) ---
    int l = t & 63, seg = t >> 6;
    int gi = b * 64 + l;
    unsigned long long kg = keys[gi];
    int partial = 0;
    int jb = seg * 256;
#pragma unroll 4
    for (int j = jb; j < jb + 256; ++j)
        partial += (keys[j] < kg) ? 1 : 0;
    pr[t] = partial;
    __syncthreads();

    // --- phase B2: full prep for own gaussian, write at sorted slot ---
    if (t < 64) {
        int i = b * 64 + t;
        int rank = pr[t] + pr[t+64] + pr[t+128] + pr[t+192];

        float p0 = pos[i*3+0], p1 = pos[i*3+1], p2 = pos[i*3+2];
        float xc = T0*p0 + T1*p1 + T2*p2  + T3;
        float yc = T4*p0 + T5*p1 + T6*p2  + T7;
        float zc = T8*p0 + T9*p1 + T10*p2 + T11;
        float az = fabsf(zc);
        bool valid = (az > NEARc) && (az < FARc) &&
                     (fabsf(xc) < az * xfac) && (fabsf(yc) < az * yfac);

        float zs = (az < 1e-8f) ? 1e-8f : zc;
        float iz = 1.0f / zs;
        float u = FXc * xc * iz + CXc;
        float v = FYc * yc * iz + CYc;

        float qw = rot[i*4+0], qx = rot[i*4+1], qy = rot[i*4+2], qz = rot[i*4+3];
        float qn = sqrtf(qw*qw + qx*qx + qy*qy + qz*qz) + 1e-12f;
        float inq = 1.0f / qn;
        qw *= inq; qx *= inq; qy *= inq; qz *= inq;
        float R00 = 1.0f - 2.0f*(qy*qy + qz*qz);
        float R01 = 2.0f*(qx*qy - qw*qz);
        float R02 = 2.0f*(qx*qz + qw*qy);
        float R10 = 2.0f*(qx*qy + qw*qz);
        float R11 = 1.0f - 2.0f*(qx*qx + qz*qz);
        float R12 = 2.0f*(qy*qz - qw*qx);
        float R20 = 2.0f*(qx*qz - qw*qy);
        float R21 = 2.0f*(qy*qz + qw*qx);
        float R22 = 1.0f - 2.0f*(qx*qx + qy*qy);

        float s0 = expf(scl[i*3+0]);
        float s1 = expf(scl[i*3+1]);
        float s2 = expf(scl[i*3+2]);
        float M00 = R00*s0, M01 = R01*s1, M02 = R02*s2;
        float M10 = R10*s0, M11 = R11*s1, M12 = R12*s2;
        float M20 = R20*s0, M21 = R21*s1, M22 = R22*s2;

        float S00 = M00*M00 + M01*M01 + M02*M02;
        float S01 = M00*M10 + M01*M11 + M02*M12;
        float S02 = M00*M20 + M01*M21 + M02*M22;
        float S11 = M10*M10 + M11*M11 + M12*M12;
        float S12 = M10*M20 + M11*M21 + M12*M22;
        float S22 = M20*M20 + M21*M21 + M22*M22;

        float j00 = FXc * iz,  j02 = -FXc * xc * iz * iz;
        float j11 = FYc * iz,  j12 = -FYc * yc * iz * iz;
        float c00v = j00*j00*S00 + 2.0f*j00*j02*S02 + j02*j02*S22 + 0.3f;
        float c01v = j00*j11*S01 + j00*j12*S02 + j02*j11*S12 + j02*j12*S22;
        float c11v = j11*j11*S11 + 2.0f*j11*j12*S12 + j12*j12*S22 + 0.3f;
        float det = fmaxf(c00v*c11v - c01v*c01v, 1e-12f);
        float idet = 1.0f / det;
        float Ai = c11v * idet;
        float Bi = -c01v * idet;
        float Ci = c00v * idet;

        float op = valid ? opac[i] : 0.0f;

        float Q = fmaxf(2.0f * logf(fmaxf(op, 1e-20f) * 1e5f), 0.0f);
        float rx = valid ? (sqrtf(Q * c00v) + 1e-3f) : -1e9f;
        float ry = valid ? (sqrtf(Q * c11v) + 1e-3f) : -1e9f;

        float pn = sqrtf(xc*xc + yc*yc + zc*zc) + 1e-12f;
        float ipn = 1.0f / pn;
        float dx = xc*ipn, dy = yc*ipn, dz = zc*ipn;
        float xx = dx*dx, yy = dy*dy, zz = dz*dz;
        float xy = dx*dy, yz = dy*dz, xz = dx*dz;

        const float* s = sh + i*48;
        float col[3];
#pragma unroll
        for (int ch = 0; ch < 3; ++ch) {
            float c = SH_C0*s[0+ch] - SH_C1*dy*s[3+ch] + SH_C1*dz*s[6+ch] - SH_C1*dx*s[9+ch];
            c += SH_C2_0*xy*s[12+ch] + SH_C2_1*yz*s[15+ch] + SH_C2_2*(2.0f*zz-xx-yy)*s[18+ch]
               + SH_C2_3*xz*s[21+ch] + SH_C2_4*(xx-yy)*s[24+ch];
            c += SH_C3_0*dy*(3.0f*xx-yy)*s[27+ch] + SH_C3_1*xy*dz*s[30+ch]
               + SH_C3_2*dy*(4.0f*zz-xx-yy)*s[33+ch] + SH_C3_3*dz*(2.0f*zz-3.0f*xx-3.0f*yy)*s[36+ch]
               + SH_C3_4*dx*(4.0f*zz-xx-yy)*s[39+ch] + SH_C3_5*dz*(xx-yy)*s[42+ch]
               + SH_C3_6*dx*(xx-3.0f*yy)*s[45+ch];
            col[ch] = fminf(fmaxf(c + 0.5f, 0.0f), 1.0f);
        }

        __half2 rg = __floats2half2_rn(col[0], col[1]);
        __half2 bz = __floats2half2_rn(col[2], zc);

        c0[rank] = make_float4(u, v, rx, ry);
        g1[rank] = make_float4(Ai, Bi, Ci, op);
        g2[rank] = make_float2(__uint_as_float(*(unsigned int*)&rg),
                               __uint_as_float(*(unsigned int*)&bz));
    }
}

// One 8x8 tile per 1-wave block (768 blocks). Input globally z-sorted, so
// ballot-compaction preserves depth order. Cull reads only 16 B/gaussian;
// full records loaded for survivors only. Early exit skips remaining chunks.
__global__ __launch_bounds__(64)
void gs_tile(const float4* __restrict__ c0, const float4* __restrict__ g1,
             const float2* __restrict__ g2, float* __restrict__ out) {
    __shared__ float4 ls0[64], ls1[64];               // 2 KB

    int lane = threadIdx.x;
    float tx0 = (float)(blockIdx.x * 8) + 0.5f;
    float tx1 = tx0 + 7.0f;
    float ty0 = (float)(blockIdx.y * 8) + 0.5f;
    float ty1 = ty0 + 7.0f;

    float px = tx0 + (float)(lane & 7);
    float py = ty0 + (float)(lane >> 3);
    float T = 1.0f;
    float cr = 0.0f, cg = 0.0f, cb = 0.0f, cd = 0.0f;

    for (int c = 0; c < NG/64; ++c) {
        int i = c * 64 + lane;
        float4 a = c0[i];
        bool pass = (a.x + a.z >= tx0) && (a.x - a.z <= tx1) &&
                    (a.y + a.w >= ty0) && (a.y - a.w <= ty1);
        unsigned long long m = __ballot(pass);
        if (m == 0ull) continue;
        if (pass) {
            int slot = __popcll(m & ((1ull << lane) - 1ull));
            float4 b = g1[i];
            float2 cc = g2[i];
            ls0[slot] = make_float4(a.x, a.y, b.x, b.y);   // u,v,A,B
            ls1[slot] = make_float4(b.z, b.w, cc.x, cc.y); // C,op,rg,bz
        }
        __syncthreads();
        int mt = __popcll(m);
        for (int j = 0; j < mt; ++j) {
            float4 b0 = ls0[j];
            float4 b1 = ls1[j];
            float dx = px - b0.x;
            float dy = py - b0.y;
            float pw = -0.5f * (b0.z * dx * dx + b1.x * dy * dy) - b0.w * dx * dy;
            pw = fminf(pw, 0.0f);
            float alpha = fminf(0.99f, b1.y * __expf(pw));
            float aeff = (alpha >= ALPHA_THRc) ? alpha : 0.0f;
            float w = aeff * T;
            float2 rg = __half22float2(*(__half2*)&b1.z);
            float2 bz = __half22float2(*(__half2*)&b1.w);
            cr += w * rg.x;
            cg += w * rg.y;
            cb += w * bz.x;
            cd += w * bz.y;
            T *= 1.0f - aeff;
        }
        __syncthreads();
        if (__all(T < 1e-4f)) break;
    }

    int x = blockIdx.x * 8 + (lane & 7);
    int y = blockIdx.y * 8 + (lane >> 3);
    int idx = y * IMW + x;
    out[idx*3 + 0] = cr;
    out[idx*3 + 1] = cg;
    out[idx*3 + 2] = cb;
    out[NPIX*3 + idx] = cd;
}

extern "C" void kernel_launch(void* const* d_in, const int* in_sizes, int n_in,
                              void* d_out, int out_size, void* d_ws, size_t ws_size,
                              hipStream_t stream) {
    const float* pos  = (const float*)d_in[0];
    const float* rot  = (const float*)d_in[1];
    const float* scl  = (const float*)d_in[2];
    const float* opac = (const float*)d_in[3];
    const float* sh   = (const float*)d_in[4];
    const float* Twc  = (const float*)d_in[5];
    float* out = (float*)d_out;

    char* ws = (char*)d_ws;
    float4* c0 = (float4*)ws;
    float4* g1 = (float4*)(ws + 16384);
    float2* g2 = (float2*)(ws + 32768);

    gs_prepsort<<<dim3(NG/64), dim3(256), 0, stream>>>(pos, rot, scl, opac, sh,
                                                       Twc, c0, g1, g2);
    gs_tile<<<dim3(IMW/8, IMH/8), dim3(64), 0, stream>>>(c0, g1, g2, out);
}